// Round 2
// baseline (995.788 us; speedup 1.0000x reference)
//
#include <hip/hip_runtime.h>

// Problem constants (from reference): B=256, N=512, M=1024, TAU=1.0
#define GSM_B 256
#define GSM_N 512
#define GSM_M 1024

#define ROWS_PER_WAVE 4
#define WAVES_PER_BLOCK 4
#define ROWS_PER_BLOCK (ROWS_PER_WAVE * WAVES_PER_BLOCK)  // 16
#define TOTAL_ROWS (GSM_B * GSM_N)                        // 131072

#define LOG2E 1.44269504088896340736f

// ---- ROUND-2 DISCRIMINATING PROBE ----
// 4 extra cold read-passes over g (+2 GB HBM fetch, outputs unchanged).
// Purpose: decide whether the main kernel is ~90 us (BW floor; dur_us is
// harness-dominated) or ~320 us (1.6 TB/s effective; real problem).
// If kernel-at-floor: dur_us +~320, kernel appears in top-5 at ~6 TB/s.
// If kernel-slow: dur_us +~1300, kernel top-1 with diagnostic counters.
#define PROBE_PASSES 4

typedef __attribute__((ext_vector_type(4))) float f32x4;

// Stage 1: lp[n,m] = logits[n,m] * log2(e), written into the workspace.
__global__ __launch_bounds__(256) void gsm_prep_lp(
    const float* __restrict__ logits, float* __restrict__ lp)
{
    const int i = blockIdx.x * 256 + threadIdx.x;   // 0 .. N*M/4 - 1
    f32x4 v = reinterpret_cast<const f32x4*>(logits)[i];
    f32x4 o;
    o.x = v.x * LOG2E;
    o.y = v.y * LOG2E;
    o.z = v.z * LOG2E;
    o.w = v.w * LOG2E;
    reinterpret_cast<f32x4*>(lp)[i] = o;
}

// One 64-lane wave processes 4 consecutive (b,n) rows (same b). Single-pass
// softmax-dot WITHOUT max subtraction (z <= ~16.7 -> exp safely in fp32 range,
// sums cancellation-free). One-row-ahead double buffering of g (nontemporal)
// and lp (L2-hot); exp2+fma via pre-scaled lp.
__global__ __launch_bounds__(256, 4) void gsm_rowsoftmax_dot_kernel(
    const float* __restrict__ x,       // [B, M]
    const float* __restrict__ lp,      // [N, M] = logits * log2e
    const float* __restrict__ g,       // [B, N, M]
    float* __restrict__ out)           // [B, N]
{
    const int wave = threadIdx.x >> 6;                       // 0..3
    const int lane = threadIdx.x & 63;                       // 0..63
    const int row0 = blockIdx.x * ROWS_PER_BLOCK + wave * ROWS_PER_WAVE;
    const int b    = row0 >> 9;                              // row0 / 512
    const int n0   = row0 & (GSM_N - 1);                     // row0 % 512

    // x row for this b: 1024 floats / 64 lanes = 4 float4 per lane (cached).
    const f32x4* __restrict__ xv = reinterpret_cast<const f32x4*>(x + (size_t)b * GSM_M);
    f32x4 xs[4];
    #pragma unroll
    for (int j = 0; j < 4; ++j)
        xs[j] = xv[j * 64 + lane];

    // Double-buffered row staging: 2 x (4 g-vectors + 4 lp-vectors).
    f32x4 gbuf[2][4], lbuf[2][4];

    {   // prefetch row 0
        const f32x4* __restrict__ gv =
            reinterpret_cast<const f32x4*>(g + (size_t)row0 * GSM_M);
        const f32x4* __restrict__ lv =
            reinterpret_cast<const f32x4*>(lp + (size_t)n0 * GSM_M);
        #pragma unroll
        for (int j = 0; j < 4; ++j) {
            gbuf[0][j] = __builtin_nontemporal_load(&gv[j * 64 + lane]);
            lbuf[0][j] = lv[j * 64 + lane];
        }
    }

    float s0[ROWS_PER_WAVE];  // sum exp(z)
    float s1[ROWS_PER_WAVE];  // sum exp(z) * x

    #pragma unroll
    for (int r = 0; r < ROWS_PER_WAVE; ++r) {
        // Issue next row's loads before touching this row's data.
        if (r + 1 < ROWS_PER_WAVE) {
            const f32x4* __restrict__ gv =
                reinterpret_cast<const f32x4*>(g + (size_t)(row0 + r + 1) * GSM_M);
            const f32x4* __restrict__ lv =
                reinterpret_cast<const f32x4*>(lp + (size_t)(n0 + r + 1) * GSM_M);
            #pragma unroll
            for (int j = 0; j < 4; ++j) {
                gbuf[(r + 1) & 1][j] = __builtin_nontemporal_load(&gv[j * 64 + lane]);
                lbuf[(r + 1) & 1][j] = lv[j * 64 + lane];
            }
        }

        float a0 = 0.0f, a1 = 0.0f;
        #pragma unroll
        for (int j = 0; j < 4; ++j) {
            const f32x4 gg = gbuf[r & 1][j];
            const f32x4 ll = lbuf[r & 1][j];
            const float z0 = __builtin_fmaf(gg.x, LOG2E, ll.x);
            const float z1 = __builtin_fmaf(gg.y, LOG2E, ll.y);
            const float z2 = __builtin_fmaf(gg.z, LOG2E, ll.z);
            const float z3 = __builtin_fmaf(gg.w, LOG2E, ll.w);
            const float e0 = __builtin_amdgcn_exp2f(z0);
            const float e1 = __builtin_amdgcn_exp2f(z1);
            const float e2 = __builtin_amdgcn_exp2f(z2);
            const float e3 = __builtin_amdgcn_exp2f(z3);
            a0 += (e0 + e1) + (e2 + e3);
            a1 += (e0 * xs[j].x + e1 * xs[j].y) + (e2 * xs[j].z + e3 * xs[j].w);
        }
        s0[r] = a0;
        s1[r] = a1;
    }

#if PROBE_PASSES > 0
    // --- BW probe: 4 cold passes over far-ahead g rows (+2 GB fetch). ---
    // Rows 65536.. ahead (mod TOTAL_ROWS): owner blocks haven't run yet,
    // so these lines are guaranteed cold. Coalesced, nontemporal.
    float junk = 0.0f;
    #pragma unroll
    for (int p = 0; p < PROBE_PASSES; ++p) {
        #pragma unroll
        for (int r = 0; r < ROWS_PER_WAVE; ++r) {
            const int prow = (row0 + r + 65536 + (p << 13)) & (TOTAL_ROWS - 1);
            const f32x4* __restrict__ pv =
                reinterpret_cast<const f32x4*>(g + (size_t)prow * GSM_M);
            #pragma unroll
            for (int j = 0; j < 4; ++j) {
                const f32x4 q = __builtin_nontemporal_load(&pv[j * 64 + lane]);
                junk += (q.x + q.y) + (q.z + q.w);
            }
        }
    }
    asm volatile("" :: "v"(junk));   // keep probe loads live (no DCE), no output effect
#endif

    // Wave-wide sum reduction: 6 steps, 8 independent swizzles per step.
    #pragma unroll
    for (int off = 1; off < 64; off <<= 1) {
        float t0[ROWS_PER_WAVE], t1[ROWS_PER_WAVE];
        #pragma unroll
        for (int r = 0; r < ROWS_PER_WAVE; ++r) {
            t0[r] = __shfl_xor(s0[r], off, 64);
            t1[r] = __shfl_xor(s1[r], off, 64);
        }
        #pragma unroll
        for (int r = 0; r < ROWS_PER_WAVE; ++r) {
            s0[r] += t0[r];
            s1[r] += t1[r];
        }
    }

    if (lane == 0) {
        f32x4 res;
        res.x = s1[0] / s0[0];
        res.y = s1[1] / s0[1];
        res.z = s1[2] / s0[2];
        res.w = s1[3] / s0[3];
        *reinterpret_cast<f32x4*>(out + row0) = res;   // 4 consecutive outputs
    }
}

// Fallback (no/too-small workspace): original math path reading raw logits.
__global__ __launch_bounds__(256, 4) void gsm_rowsoftmax_dot_kernel_raw(
    const float* __restrict__ x,
    const float* __restrict__ logits,
    const float* __restrict__ g,
    float* __restrict__ out)
{
    const int wave = threadIdx.x >> 6;
    const int lane = threadIdx.x & 63;
    const int row0 = blockIdx.x * ROWS_PER_BLOCK + wave * ROWS_PER_WAVE;
    const int b    = row0 >> 9;
    const int n0   = row0 & (GSM_N - 1);

    const f32x4* __restrict__ xv = reinterpret_cast<const f32x4*>(x + (size_t)b * GSM_M);
    f32x4 xs[4];
    #pragma unroll
    for (int j = 0; j < 4; ++j)
        xs[j] = xv[j * 64 + lane];

    float s0[ROWS_PER_WAVE], s1[ROWS_PER_WAVE];

    #pragma unroll
    for (int r = 0; r < ROWS_PER_WAVE; ++r) {
        const f32x4* __restrict__ gv =
            reinterpret_cast<const f32x4*>(g + (size_t)(row0 + r) * GSM_M);
        const f32x4* __restrict__ lv =
            reinterpret_cast<const f32x4*>(logits + (size_t)(n0 + r) * GSM_M);
        float a0 = 0.0f, a1 = 0.0f;
        #pragma unroll
        for (int j = 0; j < 4; ++j) {
            const int idx4 = j * 64 + lane;
            const f32x4 gg = __builtin_nontemporal_load(&gv[idx4]);
            const f32x4 ll = lv[idx4];
            const float e0 = __expf(ll.x + gg.x);
            const float e1 = __expf(ll.y + gg.y);
            const float e2 = __expf(ll.z + gg.z);
            const float e3 = __expf(ll.w + gg.w);
            a0 += (e0 + e1) + (e2 + e3);
            a1 += (e0 * xs[j].x + e1 * xs[j].y) + (e2 * xs[j].z + e3 * xs[j].w);
        }
        s0[r] = a0;
        s1[r] = a1;
    }

    #pragma unroll
    for (int off = 1; off < 64; off <<= 1) {
        float t0[ROWS_PER_WAVE], t1[ROWS_PER_WAVE];
        #pragma unroll
        for (int r = 0; r < ROWS_PER_WAVE; ++r) {
            t0[r] = __shfl_xor(s0[r], off, 64);
            t1[r] = __shfl_xor(s1[r], off, 64);
        }
        #pragma unroll
        for (int r = 0; r < ROWS_PER_WAVE; ++r) {
            s0[r] += t0[r];
            s1[r] += t1[r];
        }
    }

    if (lane == 0) {
        f32x4 res;
        res.x = s1[0] / s0[0];
        res.y = s1[1] / s0[1];
        res.z = s1[2] / s0[2];
        res.w = s1[3] / s0[3];
        *reinterpret_cast<f32x4*>(out + row0) = res;
    }
}

extern "C" void kernel_launch(void* const* d_in, const int* in_sizes, int n_in,
                              void* d_out, int out_size, void* d_ws, size_t ws_size,
                              hipStream_t stream) {
    const float* x      = (const float*)d_in[0];  // [B, M]
    const float* logits = (const float*)d_in[1];  // [N, M]
    const float* g      = (const float*)d_in[2];  // [B, N, M]
    float* out          = (float*)d_out;          // [B, N]

    const int rows   = TOTAL_ROWS;                // 131072
    const int blocks = rows / ROWS_PER_BLOCK;     // 8192 blocks of 256 threads

    const size_t lp_bytes = (size_t)GSM_N * GSM_M * sizeof(float);  // 2 MB
    if (d_ws != nullptr && ws_size >= lp_bytes) {
        float* lp = (float*)d_ws;
        gsm_prep_lp<<<(GSM_N * GSM_M / 4) / 256, 256, 0, stream>>>(logits, lp);
        gsm_rowsoftmax_dot_kernel<<<blocks, 256, 0, stream>>>(x, lp, g, out);
    } else {
        gsm_rowsoftmax_dot_kernel_raw<<<blocks, 256, 0, stream>>>(x, logits, g, out);
    }
}

// Round 3
// 654.827 us; speedup vs baseline: 1.5207x; 1.5207x over previous
//
#include <hip/hip_runtime.h>

// Problem constants (from reference): B=256, N=512, M=1024, TAU=1.0
#define GSM_B 256
#define GSM_N 512
#define GSM_M 1024

#define ROWS_PER_WAVE 4
#define WAVES_PER_BLOCK 4
#define ROWS_PER_BLOCK (ROWS_PER_WAVE * WAVES_PER_BLOCK)  // 16

typedef __attribute__((ext_vector_type(4))) float f32x4;

// One 64-lane wave processes 4 consecutive (b,n) rows (same b, so the x row is
// loaded once into registers). Single-pass softmax-dot WITHOUT max subtraction:
//   jax gumbel = -log(-log(u)), u <= 1-2^-24  =>  gumbel <= ~16.64
//   logits in [-1/32, 1/32]  =>  z <= 16.68, exp(z) <= 1.8e7, row sum <= 2e10
// -- all safely inside fp32 range, and both sums are cancellation-free.
// Gumbel (512 MB, read-once) is loaded non-temporally to keep logits/x in L2.
//
// Measured decomposition (round-2 probe): this kernel ~105 us (~4.9 TB/s on
// the 512 MB read-once stream, 78% of copy-achievable); the rest of dur_us is
// fixed harness cost (2 GiB workspace poison-fill ~336 us + reset dispatches
// ~215 us). VALUBusy ~11% -> exp/fma math is not on the critical path, so no
// prep kernel (its extra dispatch costs more than the VALU it saves).
__global__ __launch_bounds__(256) void gsm_rowsoftmax_dot_kernel(
    const float* __restrict__ x,       // [B, M]
    const float* __restrict__ logits,  // [N, M]
    const float* __restrict__ g,       // [B, N, M]
    float* __restrict__ out)           // [B, N]
{
    const int wave = threadIdx.x >> 6;                       // 0..3
    const int lane = threadIdx.x & 63;                       // 0..63
    const int row0 = blockIdx.x * ROWS_PER_BLOCK + wave * ROWS_PER_WAVE;
    const int b    = row0 >> 9;                              // row0 / 512
    const int n0   = row0 & (GSM_N - 1);                     // row0 % 512

    // x row for this b: 1024 floats / 64 lanes = 4 float4 per lane (cached).
    const f32x4* __restrict__ xv = reinterpret_cast<const f32x4*>(x + (size_t)b * GSM_M);
    f32x4 xs[4];
    #pragma unroll
    for (int j = 0; j < 4; ++j)
        xs[j] = xv[j * 64 + lane];

    float s0[ROWS_PER_WAVE];  // sum exp(z)
    float s1[ROWS_PER_WAVE];  // sum exp(z) * x

    #pragma unroll
    for (int r = 0; r < ROWS_PER_WAVE; ++r) {
        const f32x4* __restrict__ gv =
            reinterpret_cast<const f32x4*>(g + (size_t)(row0 + r) * GSM_M);
        const f32x4* __restrict__ lv =
            reinterpret_cast<const f32x4*>(logits + (size_t)(n0 + r) * GSM_M);

        float a0 = 0.0f, a1 = 0.0f;
        #pragma unroll
        for (int j = 0; j < 4; ++j) {
            const int idx4 = j * 64 + lane;
            const f32x4 gg = __builtin_nontemporal_load(&gv[idx4]);  // streaming
            const f32x4 ll = lv[idx4];                               // L2-hot
            const float e0 = __expf(ll.x + gg.x);
            const float e1 = __expf(ll.y + gg.y);
            const float e2 = __expf(ll.z + gg.z);
            const float e3 = __expf(ll.w + gg.w);
            a0 += (e0 + e1) + (e2 + e3);
            a1 += (e0 * xs[j].x + e1 * xs[j].y) + (e2 * xs[j].z + e3 * xs[j].w);
        }
        s0[r] = a0;
        s1[r] = a1;
    }

    // Wave-wide sum reduction: 6 steps, 8 independent swizzles per step.
    #pragma unroll
    for (int off = 1; off < 64; off <<= 1) {
        float t0[ROWS_PER_WAVE], t1[ROWS_PER_WAVE];
        #pragma unroll
        for (int r = 0; r < ROWS_PER_WAVE; ++r) {
            t0[r] = __shfl_xor(s0[r], off, 64);
            t1[r] = __shfl_xor(s1[r], off, 64);
        }
        #pragma unroll
        for (int r = 0; r < ROWS_PER_WAVE; ++r) {
            s0[r] += t0[r];
            s1[r] += t1[r];
        }
    }

    if (lane == 0) {
        f32x4 res;
        res.x = s1[0] / s0[0];
        res.y = s1[1] / s0[1];
        res.z = s1[2] / s0[2];
        res.w = s1[3] / s0[3];
        *reinterpret_cast<f32x4*>(out + row0) = res;   // 4 consecutive outputs
    }
}

extern "C" void kernel_launch(void* const* d_in, const int* in_sizes, int n_in,
                              void* d_out, int out_size, void* d_ws, size_t ws_size,
                              hipStream_t stream) {
    const float* x      = (const float*)d_in[0];  // [B, M]
    const float* logits = (const float*)d_in[1];  // [N, M]
    const float* g      = (const float*)d_in[2];  // [B, N, M]
    float* out          = (float*)d_out;          // [B, N]

    const int rows   = GSM_B * GSM_N;             // 131072
    const int blocks = rows / ROWS_PER_BLOCK;     // 8192 blocks of 256 threads
    gsm_rowsoftmax_dot_kernel<<<blocks, 256, 0, stream>>>(x, logits, g, out);
}